// Round 1
// baseline (5078.574 us; speedup 1.0000x reference)
//
#include <hip/hip_runtime.h>
#include <hip/hip_bf16.h>

#define N_NODES 50000
#define N_EDGES 800000
#define HID 128

// ---------------- degree / norm ----------------
__global__ void k_deg_init(float* deg) {
    int i = blockIdx.x * blockDim.x + threadIdx.x;
    if (i < N_NODES) deg[i] = 1.0f;  // self-loop contributes 1
}

__global__ void k_deg_count(const int* __restrict__ ei, float* deg) {
    int e = blockIdx.x * blockDim.x + threadIdx.x;
    if (e < N_EDGES) atomicAdd(&deg[ei[N_EDGES + e]], 1.0f);
}

__global__ void k_deg_fin(float* deg) {
    int i = blockIdx.x * blockDim.x + threadIdx.x;
    if (i < N_NODES) deg[i] = rsqrtf(deg[i]);  // deg >= 1 always
}

// ---------------- encoder: h0 = x @ W_enc + b (PRE-activation stored) ----------------
__global__ void k_encoder(const float* __restrict__ x, const float* __restrict__ W,
                          const float* __restrict__ b, float* __restrict__ h) {
    int i = blockIdx.x * blockDim.x + threadIdx.x;  // exactly N*128 threads
    int n = i >> 7, j = i & 127;
    float4 xv = *(const float4*)(x + (size_t)n * 4);
    float acc = b[j];
    acc += xv.x * W[0 * 128 + j];
    acc += xv.y * W[1 * 128 + j];
    acc += xv.z * W[2 * 128 + j];
    acc += xv.w * W[3 * 128 + j];
    h[i] = acc;
}

// ---------------- node GEMM: out = relu(in) @ W ; in,out [M,128], W [128,128] ----------------
__global__ __launch_bounds__(256) void k_gemm_node(const float* __restrict__ in,
                                                   const float* __restrict__ W,
                                                   float* __restrict__ out, int M) {
    __shared__ float As[64][33];   // 64 rows x 32 k (+1 pad)
    __shared__ float Ws[32][128];  // 32 k x 128 cols
    int tid = threadIdx.x;
    int rc = tid & 15;   // row group: rows rc*4 .. rc*4+3
    int jc = tid >> 4;   // col group: cols jc*8 .. jc*8+7
    int r0 = blockIdx.x * 64;

    float acc[4][8];
#pragma unroll
    for (int i = 0; i < 4; ++i)
#pragma unroll
        for (int j = 0; j < 8; ++j) acc[i][j] = 0.f;

    for (int kk = 0; kk < 128; kk += 32) {
        // stage A (relu on load), 64x32 floats
#pragma unroll
        for (int p = 0; p < 2; ++p) {
            int id = tid + p * 256;
            int row = id >> 3, q = id & 7;
            int gr = r0 + row;
            if (gr >= M) gr = M - 1;  // clamp (results unused)
            float4 v = *(const float4*)(in + (size_t)gr * 128 + kk + q * 4);
            As[row][q * 4 + 0] = fmaxf(v.x, 0.f);
            As[row][q * 4 + 1] = fmaxf(v.y, 0.f);
            As[row][q * 4 + 2] = fmaxf(v.z, 0.f);
            As[row][q * 4 + 3] = fmaxf(v.w, 0.f);
        }
        // stage W chunk, 32x128 floats
#pragma unroll
        for (int p = 0; p < 4; ++p) {
            int id = tid + p * 256;
            int k = id >> 5, q = id & 31;
            *(float4*)&Ws[k][q * 4] = *(const float4*)(W + (size_t)(kk + k) * 128 + q * 4);
        }
        __syncthreads();
#pragma unroll
        for (int k = 0; k < 32; ++k) {
            float a0 = As[rc * 4 + 0][k];
            float a1 = As[rc * 4 + 1][k];
            float a2 = As[rc * 4 + 2][k];
            float a3 = As[rc * 4 + 3][k];
            float4 w0 = *(float4*)&Ws[k][jc * 8];
            float4 w1 = *(float4*)&Ws[k][jc * 8 + 4];
            acc[0][0] += a0 * w0.x; acc[0][1] += a0 * w0.y; acc[0][2] += a0 * w0.z; acc[0][3] += a0 * w0.w;
            acc[0][4] += a0 * w1.x; acc[0][5] += a0 * w1.y; acc[0][6] += a0 * w1.z; acc[0][7] += a0 * w1.w;
            acc[1][0] += a1 * w0.x; acc[1][1] += a1 * w0.y; acc[1][2] += a1 * w0.z; acc[1][3] += a1 * w0.w;
            acc[1][4] += a1 * w1.x; acc[1][5] += a1 * w1.y; acc[1][6] += a1 * w1.z; acc[1][7] += a1 * w1.w;
            acc[2][0] += a2 * w0.x; acc[2][1] += a2 * w0.y; acc[2][2] += a2 * w0.z; acc[2][3] += a2 * w0.w;
            acc[2][4] += a2 * w1.x; acc[2][5] += a2 * w1.y; acc[2][6] += a2 * w1.z; acc[2][7] += a2 * w1.w;
            acc[3][0] += a3 * w0.x; acc[3][1] += a3 * w0.y; acc[3][2] += a3 * w0.z; acc[3][3] += a3 * w0.w;
            acc[3][4] += a3 * w1.x; acc[3][5] += a3 * w1.y; acc[3][6] += a3 * w1.z; acc[3][7] += a3 * w1.w;
        }
        __syncthreads();
    }
#pragma unroll
    for (int i = 0; i < 4; ++i) {
        int gr = r0 + rc * 4 + i;
        if (gr < M) {
            float4 o0 = make_float4(acc[i][0], acc[i][1], acc[i][2], acc[i][3]);
            float4 o1 = make_float4(acc[i][4], acc[i][5], acc[i][6], acc[i][7]);
            *(float4*)(out + (size_t)gr * 128 + jc * 8) = o0;
            *(float4*)(out + (size_t)gr * 128 + jc * 8 + 4) = o1;
        }
    }
}

// ---------------- scatter init: h_next = b + hw * dinv^2 (self loop) ----------------
__global__ void k_scatter_init(const float* __restrict__ hw, const float* __restrict__ b,
                               const float* __restrict__ dinv, float* __restrict__ h_next) {
    int i = blockIdx.x * blockDim.x + threadIdx.x;  // exactly N*128
    int n = i >> 7, j = i & 127;
    float di = dinv[n];
    h_next[i] = b[j] + hw[i] * di * di;
}

// ---------------- scatter edges: h_next[dst] += hw[src] * dinv[s]*dinv[d] ----------------
__global__ void k_scatter_edges(const float* __restrict__ hw, const float* __restrict__ dinv,
                                const int* __restrict__ ei, float* __restrict__ h_next) {
    int t = blockIdx.x * blockDim.x + threadIdx.x;
    int e = t >> 5;  // 32 lanes per edge
    int l = t & 31;
    if (e < N_EDGES) {
        int s = ei[e];
        int d = ei[N_EDGES + e];
        float w = dinv[s] * dinv[d];
        float4 v = *(const float4*)(hw + (size_t)s * 128 + l * 4);
        float* dst = h_next + (size_t)d * 128 + l * 4;
        atomicAdd(dst + 0, v.x * w);
        atomicAdd(dst + 1, v.y * w);
        atomicAdd(dst + 2, v.z * w);
        atomicAdd(dst + 3, v.w * w);
    }
}

// ---------------- edge MLP: out = relu([h[s],h[d]] @ W1 + b1) @ W2 + b2 ----------------
__global__ __launch_bounds__(256) void k_edge_mlp(const float* __restrict__ h,
                                                  const int* __restrict__ ei,
                                                  const float* __restrict__ W1,
                                                  const float* __restrict__ b1,
                                                  const float* __restrict__ W2,
                                                  const float* __restrict__ b2,
                                                  float* __restrict__ out) {
    __shared__ float As[64][33];
    __shared__ float Ws[32][128];
    __shared__ float red[192];  // 64 edges x 3 outputs
    int tid = threadIdx.x;
    int rc = tid & 15, jc = tid >> 4;
    int eBase = blockIdx.x * 64;

    float bj[8], w2[8][3];
#pragma unroll
    for (int jj = 0; jj < 8; ++jj) {
        bj[jj] = b1[jc * 8 + jj];
        w2[jj][0] = W2[(jc * 8 + jj) * 3 + 0];
        w2[jj][1] = W2[(jc * 8 + jj) * 3 + 1];
        w2[jj][2] = W2[(jc * 8 + jj) * 3 + 2];
    }

    float acc[4][8];
#pragma unroll
    for (int i = 0; i < 4; ++i)
#pragma unroll
        for (int j = 0; j < 8; ++j) acc[i][j] = 0.f;

    for (int kk = 0; kk < 256; kk += 32) {
        int half = kk >> 7;        // 0: src endpoint, 1: dst endpoint
        int colBase = kk & 127;    // column within h row
        // stage ef chunk (gather + relu)
#pragma unroll
        for (int p = 0; p < 2; ++p) {
            int id = tid + p * 256;
            int row = id >> 3, q = id & 7;
            int nidx = ei[half * N_EDGES + eBase + row];
            float4 v = *(const float4*)(h + (size_t)nidx * 128 + colBase + q * 4);
            As[row][q * 4 + 0] = fmaxf(v.x, 0.f);
            As[row][q * 4 + 1] = fmaxf(v.y, 0.f);
            As[row][q * 4 + 2] = fmaxf(v.z, 0.f);
            As[row][q * 4 + 3] = fmaxf(v.w, 0.f);
        }
        // stage W1 chunk
#pragma unroll
        for (int p = 0; p < 4; ++p) {
            int id = tid + p * 256;
            int k = id >> 5, q = id & 31;
            *(float4*)&Ws[k][q * 4] = *(const float4*)(W1 + (size_t)(kk + k) * 128 + q * 4);
        }
        __syncthreads();
#pragma unroll
        for (int k = 0; k < 32; ++k) {
            float a0 = As[rc * 4 + 0][k];
            float a1 = As[rc * 4 + 1][k];
            float a2 = As[rc * 4 + 2][k];
            float a3 = As[rc * 4 + 3][k];
            float4 w0 = *(float4*)&Ws[k][jc * 8];
            float4 w1 = *(float4*)&Ws[k][jc * 8 + 4];
            acc[0][0] += a0 * w0.x; acc[0][1] += a0 * w0.y; acc[0][2] += a0 * w0.z; acc[0][3] += a0 * w0.w;
            acc[0][4] += a0 * w1.x; acc[0][5] += a0 * w1.y; acc[0][6] += a0 * w1.z; acc[0][7] += a0 * w1.w;
            acc[1][0] += a1 * w0.x; acc[1][1] += a1 * w0.y; acc[1][2] += a1 * w0.z; acc[1][3] += a1 * w0.w;
            acc[1][4] += a1 * w1.x; acc[1][5] += a1 * w1.y; acc[1][6] += a1 * w1.z; acc[1][7] += a1 * w1.w;
            acc[2][0] += a2 * w0.x; acc[2][1] += a2 * w0.y; acc[2][2] += a2 * w0.z; acc[2][3] += a2 * w0.w;
            acc[2][4] += a2 * w1.x; acc[2][5] += a2 * w1.y; acc[2][6] += a2 * w1.z; acc[2][7] += a2 * w1.w;
            acc[3][0] += a3 * w0.x; acc[3][1] += a3 * w0.y; acc[3][2] += a3 * w0.z; acc[3][3] += a3 * w0.w;
            acc[3][4] += a3 * w1.x; acc[3][5] += a3 * w1.y; acc[3][6] += a3 * w1.z; acc[3][7] += a3 * w1.w;
        }
        __syncthreads();
    }

    // epilogue: z = relu(acc + b1); partial out = z @ W2
    float p3[4][3];
#pragma unroll
    for (int i = 0; i < 4; ++i) { p3[i][0] = 0.f; p3[i][1] = 0.f; p3[i][2] = 0.f; }
#pragma unroll
    for (int i = 0; i < 4; ++i) {
#pragma unroll
        for (int jj = 0; jj < 8; ++jj) {
            float z = fmaxf(acc[i][jj] + bj[jj], 0.f);
            p3[i][0] += z * w2[jj][0];
            p3[i][1] += z * w2[jj][1];
            p3[i][2] += z * w2[jj][2];
        }
    }
    if (tid < 192) red[tid] = 0.f;
    __syncthreads();
#pragma unroll
    for (int i = 0; i < 4; ++i) {
        atomicAdd(&red[(rc * 4 + i) * 3 + 0], p3[i][0]);
        atomicAdd(&red[(rc * 4 + i) * 3 + 1], p3[i][1]);
        atomicAdd(&red[(rc * 4 + i) * 3 + 2], p3[i][2]);
    }
    __syncthreads();
    if (tid < 192) {
        out[(size_t)eBase * 3 + tid] = red[tid] + b2[tid % 3];
    }
}

extern "C" void kernel_launch(void* const* d_in, const int* in_sizes, int n_in,
                              void* d_out, int out_size, void* d_ws, size_t ws_size,
                              hipStream_t stream) {
    const float* x     = (const float*)d_in[0];
    const int*   ei    = (const int*)d_in[1];
    const float* W_enc = (const float*)d_in[2];
    const float* b_enc = (const float*)d_in[3];
    const float* Wg[3] = {(const float*)d_in[4], (const float*)d_in[6], (const float*)d_in[8]};
    const float* bg[3] = {(const float*)d_in[5], (const float*)d_in[7], (const float*)d_in[9]};
    const float* W_m1  = (const float*)d_in[10];
    const float* b_m1  = (const float*)d_in[11];
    const float* W_m2  = (const float*)d_in[12];
    const float* b_m2  = (const float*)d_in[13];
    float* out = (float*)d_out;

    float* hA   = (float*)d_ws;                       // [N,128] pre-activation
    float* hB   = hA + (size_t)N_NODES * HID;         // [N,128] h@W scratch
    float* dinv = hB + (size_t)N_NODES * HID;         // [N]

    k_deg_init<<<(N_NODES + 255) / 256, 256, 0, stream>>>(dinv);
    k_deg_count<<<(N_EDGES + 255) / 256, 256, 0, stream>>>(ei, dinv);
    k_deg_fin<<<(N_NODES + 255) / 256, 256, 0, stream>>>(dinv);

    k_encoder<<<N_NODES * HID / 256, 256, 0, stream>>>(x, W_enc, b_enc, hA);

    for (int l = 0; l < 3; ++l) {
        k_gemm_node<<<(N_NODES + 63) / 64, 256, 0, stream>>>(hA, Wg[l], hB, N_NODES);
        k_scatter_init<<<N_NODES * HID / 256, 256, 0, stream>>>(hB, bg[l], dinv, hA);
        k_scatter_edges<<<N_EDGES / 8, 256, 0, stream>>>(hB, dinv, ei, hA);
    }

    k_edge_mlp<<<N_EDGES / 64, 256, 0, stream>>>(hA, ei, W_m1, b_m1, W_m2, b_m2, out);
}

// Round 2
// 1253.984 us; speedup vs baseline: 4.0500x; 4.0500x over previous
//
#include <hip/hip_runtime.h>
#include <hip/hip_bf16.h>

#define N_NODES 50000
#define N_EDGES 800000
#define HID 128
#define SCAN_BLK 512
#define N_SCAN_BLOCKS ((N_NODES + SCAN_BLK - 1) / SCAN_BLK)  // 98

// ---------------- CSR build ----------------
__global__ void k_zero_cnt(int* cnt) {
    int i = blockIdx.x * blockDim.x + threadIdx.x;
    if (i < N_NODES) cnt[i] = 0;
}

__global__ void k_count(const int* __restrict__ ei, int* cnt) {
    int e = blockIdx.x * blockDim.x + threadIdx.x;
    if (e < N_EDGES) atomicAdd(&cnt[ei[N_EDGES + e]], 1);
}

// block-wise exclusive scan of in-degree counts; also computes dinv = rsqrt(1+indeg)
__global__ __launch_bounds__(SCAN_BLK) void k_scan1(const int* __restrict__ cnt,
                                                    int* __restrict__ rowStart,
                                                    int* __restrict__ blockSums,
                                                    float* __restrict__ dinv) {
    __shared__ int tmp[SCAN_BLK];
    int i = blockIdx.x * SCAN_BLK + threadIdx.x;
    int v = (i < N_NODES) ? cnt[i] : 0;
    if (i < N_NODES) dinv[i] = rsqrtf(1.0f + (float)v);
    tmp[threadIdx.x] = v;
    __syncthreads();
    for (int off = 1; off < SCAN_BLK; off <<= 1) {
        int t = (threadIdx.x >= off) ? tmp[threadIdx.x - off] : 0;
        __syncthreads();
        tmp[threadIdx.x] += t;
        __syncthreads();
    }
    if (i < N_NODES) rowStart[i] = tmp[threadIdx.x] - v;  // exclusive
    if (threadIdx.x == SCAN_BLK - 1) blockSums[blockIdx.x] = tmp[SCAN_BLK - 1];
}

__global__ void k_scan2(int* blockSums) {
    if (blockIdx.x == 0 && threadIdx.x == 0) {
        int acc = 0;
        for (int i = 0; i < N_SCAN_BLOCKS; ++i) {
            int t = blockSums[i];
            blockSums[i] = acc;
            acc += t;
        }
    }
}

__global__ __launch_bounds__(SCAN_BLK) void k_scan3(int* __restrict__ rowStart,
                                                    const int* __restrict__ blockSums,
                                                    int* __restrict__ cursor) {
    int i = blockIdx.x * SCAN_BLK + threadIdx.x;
    if (i < N_NODES) {
        rowStart[i] += blockSums[blockIdx.x];
        cursor[i] = 0;
    }
    if (i == 0) rowStart[N_NODES] = N_EDGES;
}

// bucket fill: csr[pos] = {src, weight}
__global__ void k_fill(const int* __restrict__ ei, const float* __restrict__ dinv,
                       const int* __restrict__ rowStart, int* cursor, int2* __restrict__ csr) {
    int e = blockIdx.x * blockDim.x + threadIdx.x;
    if (e < N_EDGES) {
        int s = ei[e];
        int d = ei[N_EDGES + e];
        int pos = rowStart[d] + atomicAdd(&cursor[d], 1);
        csr[pos] = make_int2(s, __float_as_int(dinv[s] * dinv[d]));
    }
}

// ---------------- encoder: h0 = x @ W_enc + b (PRE-activation stored) ----------------
__global__ void k_encoder(const float* __restrict__ x, const float* __restrict__ W,
                          const float* __restrict__ b, float* __restrict__ h) {
    int i = blockIdx.x * blockDim.x + threadIdx.x;  // exactly N*128 threads
    int n = i >> 7, j = i & 127;
    float4 xv = *(const float4*)(x + (size_t)n * 4);
    float acc = b[j];
    acc += xv.x * W[0 * 128 + j];
    acc += xv.y * W[1 * 128 + j];
    acc += xv.z * W[2 * 128 + j];
    acc += xv.w * W[3 * 128 + j];
    h[i] = acc;
}

// ---------------- node GEMM: out = relu(in) @ W ; in,out [M,128], W [128,128] ----------------
__global__ __launch_bounds__(256) void k_gemm_node(const float* __restrict__ in,
                                                   const float* __restrict__ W,
                                                   float* __restrict__ out, int M) {
    __shared__ float As[64][33];
    __shared__ float Ws[32][128];
    int tid = threadIdx.x;
    int rc = tid & 15;
    int jc = tid >> 4;
    int r0 = blockIdx.x * 64;

    float acc[4][8];
#pragma unroll
    for (int i = 0; i < 4; ++i)
#pragma unroll
        for (int j = 0; j < 8; ++j) acc[i][j] = 0.f;

    for (int kk = 0; kk < 128; kk += 32) {
#pragma unroll
        for (int p = 0; p < 2; ++p) {
            int id = tid + p * 256;
            int row = id >> 3, q = id & 7;
            int gr = r0 + row;
            if (gr >= M) gr = M - 1;
            float4 v = *(const float4*)(in + (size_t)gr * 128 + kk + q * 4);
            As[row][q * 4 + 0] = fmaxf(v.x, 0.f);
            As[row][q * 4 + 1] = fmaxf(v.y, 0.f);
            As[row][q * 4 + 2] = fmaxf(v.z, 0.f);
            As[row][q * 4 + 3] = fmaxf(v.w, 0.f);
        }
#pragma unroll
        for (int p = 0; p < 4; ++p) {
            int id = tid + p * 256;
            int k = id >> 5, q = id & 31;
            *(float4*)&Ws[k][q * 4] = *(const float4*)(W + (size_t)(kk + k) * 128 + q * 4);
        }
        __syncthreads();
#pragma unroll
        for (int k = 0; k < 32; ++k) {
            float a0 = As[rc * 4 + 0][k];
            float a1 = As[rc * 4 + 1][k];
            float a2 = As[rc * 4 + 2][k];
            float a3 = As[rc * 4 + 3][k];
            float4 w0 = *(float4*)&Ws[k][jc * 8];
            float4 w1 = *(float4*)&Ws[k][jc * 8 + 4];
            acc[0][0] += a0 * w0.x; acc[0][1] += a0 * w0.y; acc[0][2] += a0 * w0.z; acc[0][3] += a0 * w0.w;
            acc[0][4] += a0 * w1.x; acc[0][5] += a0 * w1.y; acc[0][6] += a0 * w1.z; acc[0][7] += a0 * w1.w;
            acc[1][0] += a1 * w0.x; acc[1][1] += a1 * w0.y; acc[1][2] += a1 * w0.z; acc[1][3] += a1 * w0.w;
            acc[1][4] += a1 * w1.x; acc[1][5] += a1 * w1.y; acc[1][6] += a1 * w1.z; acc[1][7] += a1 * w1.w;
            acc[2][0] += a2 * w0.x; acc[2][1] += a2 * w0.y; acc[2][2] += a2 * w0.z; acc[2][3] += a2 * w0.w;
            acc[2][4] += a2 * w1.x; acc[2][5] += a2 * w1.y; acc[2][6] += a2 * w1.z; acc[2][7] += a2 * w1.w;
            acc[3][0] += a3 * w0.x; acc[3][1] += a3 * w0.y; acc[3][2] += a3 * w0.z; acc[3][3] += a3 * w0.w;
            acc[3][4] += a3 * w1.x; acc[3][5] += a3 * w1.y; acc[3][6] += a3 * w1.z; acc[3][7] += a3 * w1.w;
        }
        __syncthreads();
    }
#pragma unroll
    for (int i = 0; i < 4; ++i) {
        int gr = r0 + rc * 4 + i;
        if (gr < M) {
            float4 o0 = make_float4(acc[i][0], acc[i][1], acc[i][2], acc[i][3]);
            float4 o1 = make_float4(acc[i][4], acc[i][5], acc[i][6], acc[i][7]);
            *(float4*)(out + (size_t)gr * 128 + jc * 8) = o0;
            *(float4*)(out + (size_t)gr * 128 + jc * 8 + 4) = o1;
        }
    }
}

// ---------------- aggregate (gather): h_next[n] = b + hw[n]*dinv[n]^2 + sum_csr hw[src]*w ----
__global__ __launch_bounds__(256) void k_aggregate(const float* __restrict__ hw,
                                                   const float* __restrict__ b,
                                                   const float* __restrict__ dinv,
                                                   const int* __restrict__ rowStart,
                                                   const int2* __restrict__ csr,
                                                   float* __restrict__ hout) {
    int wid = (blockIdx.x * blockDim.x + threadIdx.x) >> 6;  // one wave per node
    int lane = threadIdx.x & 63;
    if (wid >= N_NODES) return;
    int n = wid;
    float di = dinv[n];
    float2 acc = *(const float2*)(b + lane * 2);
    float2 hv = *(const float2*)(hw + (size_t)n * 128 + lane * 2);
    acc.x += hv.x * di * di;
    acc.y += hv.y * di * di;
    int s0 = rowStart[n], s1 = rowStart[n + 1];
    for (int k = s0; k < s1; ++k) {
        int2 c = csr[k];
        float w = __int_as_float(c.y);
        float2 v = *(const float2*)(hw + (size_t)c.x * 128 + lane * 2);
        acc.x += v.x * w;
        acc.y += v.y * w;
    }
    *(float2*)(hout + (size_t)n * 128 + lane * 2) = acc;
}

// ---------------- edge MLP: out = relu([h[s],h[d]] @ W1 + b1) @ W2 + b2 ----------------
__global__ __launch_bounds__(256) void k_edge_mlp(const float* __restrict__ h,
                                                  const int* __restrict__ ei,
                                                  const float* __restrict__ W1,
                                                  const float* __restrict__ b1,
                                                  const float* __restrict__ W2,
                                                  const float* __restrict__ b2,
                                                  float* __restrict__ out) {
    __shared__ float As[64][33];
    __shared__ float Ws[32][128];
    __shared__ float red[192];
    int tid = threadIdx.x;
    int rc = tid & 15, jc = tid >> 4;
    int eBase = blockIdx.x * 64;

    float bj[8], w2[8][3];
#pragma unroll
    for (int jj = 0; jj < 8; ++jj) {
        bj[jj] = b1[jc * 8 + jj];
        w2[jj][0] = W2[(jc * 8 + jj) * 3 + 0];
        w2[jj][1] = W2[(jc * 8 + jj) * 3 + 1];
        w2[jj][2] = W2[(jc * 8 + jj) * 3 + 2];
    }

    float acc[4][8];
#pragma unroll
    for (int i = 0; i < 4; ++i)
#pragma unroll
        for (int j = 0; j < 8; ++j) acc[i][j] = 0.f;

    for (int kk = 0; kk < 256; kk += 32) {
        int half = kk >> 7;
        int colBase = kk & 127;
#pragma unroll
        for (int p = 0; p < 2; ++p) {
            int id = tid + p * 256;
            int row = id >> 3, q = id & 7;
            int nidx = ei[half * N_EDGES + eBase + row];
            float4 v = *(const float4*)(h + (size_t)nidx * 128 + colBase + q * 4);
            As[row][q * 4 + 0] = fmaxf(v.x, 0.f);
            As[row][q * 4 + 1] = fmaxf(v.y, 0.f);
            As[row][q * 4 + 2] = fmaxf(v.z, 0.f);
            As[row][q * 4 + 3] = fmaxf(v.w, 0.f);
        }
#pragma unroll
        for (int p = 0; p < 4; ++p) {
            int id = tid + p * 256;
            int k = id >> 5, q = id & 31;
            *(float4*)&Ws[k][q * 4] = *(const float4*)(W1 + (size_t)(kk + k) * 128 + q * 4);
        }
        __syncthreads();
#pragma unroll
        for (int k = 0; k < 32; ++k) {
            float a0 = As[rc * 4 + 0][k];
            float a1 = As[rc * 4 + 1][k];
            float a2 = As[rc * 4 + 2][k];
            float a3 = As[rc * 4 + 3][k];
            float4 w0 = *(float4*)&Ws[k][jc * 8];
            float4 w1 = *(float4*)&Ws[k][jc * 8 + 4];
            acc[0][0] += a0 * w0.x; acc[0][1] += a0 * w0.y; acc[0][2] += a0 * w0.z; acc[0][3] += a0 * w0.w;
            acc[0][4] += a0 * w1.x; acc[0][5] += a0 * w1.y; acc[0][6] += a0 * w1.z; acc[0][7] += a0 * w1.w;
            acc[1][0] += a1 * w0.x; acc[1][1] += a1 * w0.y; acc[1][2] += a1 * w0.z; acc[1][3] += a1 * w0.w;
            acc[1][4] += a1 * w1.x; acc[1][5] += a1 * w1.y; acc[1][6] += a1 * w1.z; acc[1][7] += a1 * w1.w;
            acc[2][0] += a2 * w0.x; acc[2][1] += a2 * w0.y; acc[2][2] += a2 * w0.z; acc[2][3] += a2 * w0.w;
            acc[2][4] += a2 * w1.x; acc[2][5] += a2 * w1.y; acc[2][6] += a2 * w1.z; acc[2][7] += a2 * w1.w;
            acc[3][0] += a3 * w0.x; acc[3][1] += a3 * w0.y; acc[3][2] += a3 * w0.z; acc[3][3] += a3 * w0.w;
            acc[3][4] += a3 * w1.x; acc[3][5] += a3 * w1.y; acc[3][6] += a3 * w1.z; acc[3][7] += a3 * w1.w;
        }
        __syncthreads();
    }

    float p3[4][3];
#pragma unroll
    for (int i = 0; i < 4; ++i) { p3[i][0] = 0.f; p3[i][1] = 0.f; p3[i][2] = 0.f; }
#pragma unroll
    for (int i = 0; i < 4; ++i) {
#pragma unroll
        for (int jj = 0; jj < 8; ++jj) {
            float z = fmaxf(acc[i][jj] + bj[jj], 0.f);
            p3[i][0] += z * w2[jj][0];
            p3[i][1] += z * w2[jj][1];
            p3[i][2] += z * w2[jj][2];
        }
    }
    if (tid < 192) red[tid] = 0.f;
    __syncthreads();
#pragma unroll
    for (int i = 0; i < 4; ++i) {
        atomicAdd(&red[(rc * 4 + i) * 3 + 0], p3[i][0]);
        atomicAdd(&red[(rc * 4 + i) * 3 + 1], p3[i][1]);
        atomicAdd(&red[(rc * 4 + i) * 3 + 2], p3[i][2]);
    }
    __syncthreads();
    if (tid < 192) {
        out[(size_t)eBase * 3 + tid] = red[tid] + b2[tid % 3];
    }
}

extern "C" void kernel_launch(void* const* d_in, const int* in_sizes, int n_in,
                              void* d_out, int out_size, void* d_ws, size_t ws_size,
                              hipStream_t stream) {
    const float* x     = (const float*)d_in[0];
    const int*   ei    = (const int*)d_in[1];
    const float* W_enc = (const float*)d_in[2];
    const float* b_enc = (const float*)d_in[3];
    const float* Wg[3] = {(const float*)d_in[4], (const float*)d_in[6], (const float*)d_in[8]};
    const float* bg[3] = {(const float*)d_in[5], (const float*)d_in[7], (const float*)d_in[9]};
    const float* W_m1  = (const float*)d_in[10];
    const float* b_m1  = (const float*)d_in[11];
    const float* W_m2  = (const float*)d_in[12];
    const float* b_m2  = (const float*)d_in[13];
    float* out = (float*)d_out;

    // workspace layout (bytes): hA 25.6M | hB 25.6M | csr 6.4M | dinv | rowStart | cursor | blockSums
    char* w = (char*)d_ws;
    float* hA       = (float*)w;                         w += (size_t)N_NODES * HID * 4;
    float* hB       = (float*)w;                         w += (size_t)N_NODES * HID * 4;
    int2*  csr      = (int2*)w;                          w += (size_t)N_EDGES * 8;
    float* dinv     = (float*)w;                         w += (size_t)N_NODES * 4;
    int*   rowStart = (int*)w;                           w += (size_t)(N_NODES + 1) * 4;
    int*   cursor   = (int*)w;                           w += (size_t)N_NODES * 4;
    int*   blockSums= (int*)w;

    // --- CSR build (once; reused across 3 layers) ---
    k_zero_cnt<<<(N_NODES + 255) / 256, 256, 0, stream>>>(cursor);
    k_count<<<(N_EDGES + 255) / 256, 256, 0, stream>>>(ei, cursor);
    k_scan1<<<N_SCAN_BLOCKS, SCAN_BLK, 0, stream>>>(cursor, rowStart, blockSums, dinv);
    k_scan2<<<1, 64, 0, stream>>>(blockSums);
    k_scan3<<<N_SCAN_BLOCKS, SCAN_BLK, 0, stream>>>(rowStart, blockSums, cursor);
    k_fill<<<(N_EDGES + 255) / 256, 256, 0, stream>>>(ei, dinv, rowStart, cursor, csr);

    k_encoder<<<N_NODES * HID / 256, 256, 0, stream>>>(x, W_enc, b_enc, hA);

    for (int l = 0; l < 3; ++l) {
        k_gemm_node<<<(N_NODES + 63) / 64, 256, 0, stream>>>(hA, Wg[l], hB, N_NODES);
        k_aggregate<<<(N_NODES * 64 + 255) / 256, 256, 0, stream>>>(hB, bg[l], dinv, rowStart, csr, hA);
    }

    k_edge_mlp<<<N_EDGES / 64, 256, 0, stream>>>(hA, ei, W_m1, b_m1, W_m2, b_m2, out);
}

// Round 3
// 623.262 us; speedup vs baseline: 8.1484x; 2.0120x over previous
//
#include <hip/hip_runtime.h>
#include <hip/hip_bf16.h>

#define N_NODES 50000
#define N_EDGES 800000
#define HID 128
#define SCAN_BLK 512
#define N_SCAN_BLOCKS ((N_NODES + SCAN_BLK - 1) / SCAN_BLK)  // 98

// ---------------- CSR build ----------------
__global__ void k_zero_cnt(int* cnt) {
    int i = blockIdx.x * blockDim.x + threadIdx.x;
    if (i < N_NODES) cnt[i] = 0;
}

__global__ void k_count(const int* __restrict__ ei, int* cnt) {
    int e = blockIdx.x * blockDim.x + threadIdx.x;
    if (e < N_EDGES) atomicAdd(&cnt[ei[N_EDGES + e]], 1);
}

__global__ __launch_bounds__(SCAN_BLK) void k_scan1(const int* __restrict__ cnt,
                                                    int* __restrict__ rowStart,
                                                    int* __restrict__ blockSums,
                                                    float* __restrict__ dinv) {
    __shared__ int tmp[SCAN_BLK];
    int i = blockIdx.x * SCAN_BLK + threadIdx.x;
    int v = (i < N_NODES) ? cnt[i] : 0;
    if (i < N_NODES) dinv[i] = rsqrtf(1.0f + (float)v);
    tmp[threadIdx.x] = v;
    __syncthreads();
    for (int off = 1; off < SCAN_BLK; off <<= 1) {
        int t = (threadIdx.x >= off) ? tmp[threadIdx.x - off] : 0;
        __syncthreads();
        tmp[threadIdx.x] += t;
        __syncthreads();
    }
    if (i < N_NODES) rowStart[i] = tmp[threadIdx.x] - v;  // exclusive
    if (threadIdx.x == SCAN_BLK - 1) blockSums[blockIdx.x] = tmp[SCAN_BLK - 1];
}

__global__ void k_scan2(int* blockSums) {
    if (blockIdx.x == 0 && threadIdx.x == 0) {
        int acc = 0;
        for (int i = 0; i < N_SCAN_BLOCKS; ++i) {
            int t = blockSums[i];
            blockSums[i] = acc;
            acc += t;
        }
    }
}

__global__ __launch_bounds__(SCAN_BLK) void k_scan3(int* __restrict__ rowStart,
                                                    const int* __restrict__ blockSums,
                                                    int* __restrict__ cursor) {
    int i = blockIdx.x * SCAN_BLK + threadIdx.x;
    if (i < N_NODES) {
        rowStart[i] += blockSums[blockIdx.x];
        cursor[i] = 0;
    }
    if (i == 0) rowStart[N_NODES] = N_EDGES;
}

__global__ void k_fill(const int* __restrict__ ei, const float* __restrict__ dinv,
                       const int* __restrict__ rowStart, int* cursor, int2* __restrict__ csr) {
    int e = blockIdx.x * blockDim.x + threadIdx.x;
    if (e < N_EDGES) {
        int s = ei[e];
        int d = ei[N_EDGES + e];
        int pos = rowStart[d] + atomicAdd(&cursor[d], 1);
        csr[pos] = make_int2(s, __float_as_int(dinv[s] * dinv[d]));
    }
}

// ---------------- encoder: h0 = x @ W_enc + b (PRE-activation stored) ----------------
__global__ void k_encoder(const float* __restrict__ x, const float* __restrict__ W,
                          const float* __restrict__ b, float* __restrict__ h) {
    int i = blockIdx.x * blockDim.x + threadIdx.x;  // exactly N*128 threads
    int n = i >> 7, j = i & 127;
    float4 xv = *(const float4*)(x + (size_t)n * 4);
    float acc = b[j];
    acc += xv.x * W[0 * 128 + j];
    acc += xv.y * W[1 * 128 + j];
    acc += xv.z * W[2 * 128 + j];
    acc += xv.w * W[3 * 128 + j];
    h[i] = acc;
}

// ---------------- node GEMM: out = relu(in) @ W ; in,out [M,128], W [128,128] ----------------
__global__ __launch_bounds__(256) void k_gemm_node(const float* __restrict__ in,
                                                   const float* __restrict__ W,
                                                   float* __restrict__ out, int M) {
    __shared__ float As[64][33];
    __shared__ float Ws[32][128];
    int tid = threadIdx.x;
    int rc = tid & 15;
    int jc = tid >> 4;
    int r0 = blockIdx.x * 64;

    float acc[4][8];
#pragma unroll
    for (int i = 0; i < 4; ++i)
#pragma unroll
        for (int j = 0; j < 8; ++j) acc[i][j] = 0.f;

    for (int kk = 0; kk < 128; kk += 32) {
#pragma unroll
        for (int p = 0; p < 2; ++p) {
            int id = tid + p * 256;
            int row = id >> 3, q = id & 7;
            int gr = r0 + row;
            if (gr >= M) gr = M - 1;
            float4 v = *(const float4*)(in + (size_t)gr * 128 + kk + q * 4);
            As[row][q * 4 + 0] = fmaxf(v.x, 0.f);
            As[row][q * 4 + 1] = fmaxf(v.y, 0.f);
            As[row][q * 4 + 2] = fmaxf(v.z, 0.f);
            As[row][q * 4 + 3] = fmaxf(v.w, 0.f);
        }
#pragma unroll
        for (int p = 0; p < 4; ++p) {
            int id = tid + p * 256;
            int k = id >> 5, q = id & 31;
            *(float4*)&Ws[k][q * 4] = *(const float4*)(W + (size_t)(kk + k) * 128 + q * 4);
        }
        __syncthreads();
#pragma unroll
        for (int k = 0; k < 32; ++k) {
            float a0 = As[rc * 4 + 0][k];
            float a1 = As[rc * 4 + 1][k];
            float a2 = As[rc * 4 + 2][k];
            float a3 = As[rc * 4 + 3][k];
            float4 w0 = *(float4*)&Ws[k][jc * 8];
            float4 w1 = *(float4*)&Ws[k][jc * 8 + 4];
            acc[0][0] += a0 * w0.x; acc[0][1] += a0 * w0.y; acc[0][2] += a0 * w0.z; acc[0][3] += a0 * w0.w;
            acc[0][4] += a0 * w1.x; acc[0][5] += a0 * w1.y; acc[0][6] += a0 * w1.z; acc[0][7] += a0 * w1.w;
            acc[1][0] += a1 * w0.x; acc[1][1] += a1 * w0.y; acc[1][2] += a1 * w0.z; acc[1][3] += a1 * w0.w;
            acc[1][4] += a1 * w1.x; acc[1][5] += a1 * w1.y; acc[1][6] += a1 * w1.z; acc[1][7] += a1 * w1.w;
            acc[2][0] += a2 * w0.x; acc[2][1] += a2 * w0.y; acc[2][2] += a2 * w0.z; acc[2][3] += a2 * w0.w;
            acc[2][4] += a2 * w1.x; acc[2][5] += a2 * w1.y; acc[2][6] += a2 * w1.z; acc[2][7] += a2 * w1.w;
            acc[3][0] += a3 * w0.x; acc[3][1] += a3 * w0.y; acc[3][2] += a3 * w0.z; acc[3][3] += a3 * w0.w;
            acc[3][4] += a3 * w1.x; acc[3][5] += a3 * w1.y; acc[3][6] += a3 * w1.z; acc[3][7] += a3 * w1.w;
        }
        __syncthreads();
    }
#pragma unroll
    for (int i = 0; i < 4; ++i) {
        int gr = r0 + rc * 4 + i;
        if (gr < M) {
            float4 o0 = make_float4(acc[i][0], acc[i][1], acc[i][2], acc[i][3]);
            float4 o1 = make_float4(acc[i][4], acc[i][5], acc[i][6], acc[i][7]);
            *(float4*)(out + (size_t)gr * 128 + jc * 8) = o0;
            *(float4*)(out + (size_t)gr * 128 + jc * 8 + 4) = o1;
        }
    }
}

// ---------------- fused PQ GEMM: P = relu(in)@Wt, Q = relu(in)@Wb ----------------
// outQ may alias `in` (each block reads only the rows it writes; all reads of the
// A-tile complete before the epilogue stores).
__global__ __launch_bounds__(256) void k_gemm_pq(const float* in,
                                                 const float* __restrict__ Wt,
                                                 const float* __restrict__ Wb,
                                                 float* outP, float* outQ, int M) {
    __shared__ float As[64][33];
    __shared__ float Wts[32][128];
    __shared__ float Wbs[32][128];
    int tid = threadIdx.x;
    int rc = tid & 15;
    int jc = tid >> 4;
    int r0 = blockIdx.x * 64;

    float accP[4][8], accQ[4][8];
#pragma unroll
    for (int i = 0; i < 4; ++i)
#pragma unroll
        for (int j = 0; j < 8; ++j) { accP[i][j] = 0.f; accQ[i][j] = 0.f; }

    for (int kk = 0; kk < 128; kk += 32) {
#pragma unroll
        for (int p = 0; p < 2; ++p) {
            int id = tid + p * 256;
            int row = id >> 3, q = id & 7;
            int gr = r0 + row;
            if (gr >= M) gr = M - 1;
            float4 v = *(const float4*)(in + (size_t)gr * 128 + kk + q * 4);
            As[row][q * 4 + 0] = fmaxf(v.x, 0.f);
            As[row][q * 4 + 1] = fmaxf(v.y, 0.f);
            As[row][q * 4 + 2] = fmaxf(v.z, 0.f);
            As[row][q * 4 + 3] = fmaxf(v.w, 0.f);
        }
#pragma unroll
        for (int p = 0; p < 4; ++p) {
            int id = tid + p * 256;
            int k = id >> 5, q = id & 31;
            *(float4*)&Wts[k][q * 4] = *(const float4*)(Wt + (size_t)(kk + k) * 128 + q * 4);
            *(float4*)&Wbs[k][q * 4] = *(const float4*)(Wb + (size_t)(kk + k) * 128 + q * 4);
        }
        __syncthreads();
#pragma unroll
        for (int k = 0; k < 32; ++k) {
            float a0 = As[rc * 4 + 0][k];
            float a1 = As[rc * 4 + 1][k];
            float a2 = As[rc * 4 + 2][k];
            float a3 = As[rc * 4 + 3][k];
            float4 t0 = *(float4*)&Wts[k][jc * 8];
            float4 t1 = *(float4*)&Wts[k][jc * 8 + 4];
            float4 u0 = *(float4*)&Wbs[k][jc * 8];
            float4 u1 = *(float4*)&Wbs[k][jc * 8 + 4];
            accP[0][0] += a0 * t0.x; accP[0][1] += a0 * t0.y; accP[0][2] += a0 * t0.z; accP[0][3] += a0 * t0.w;
            accP[0][4] += a0 * t1.x; accP[0][5] += a0 * t1.y; accP[0][6] += a0 * t1.z; accP[0][7] += a0 * t1.w;
            accP[1][0] += a1 * t0.x; accP[1][1] += a1 * t0.y; accP[1][2] += a1 * t0.z; accP[1][3] += a1 * t0.w;
            accP[1][4] += a1 * t1.x; accP[1][5] += a1 * t1.y; accP[1][6] += a1 * t1.z; accP[1][7] += a1 * t1.w;
            accP[2][0] += a2 * t0.x; accP[2][1] += a2 * t0.y; accP[2][2] += a2 * t0.z; accP[2][3] += a2 * t0.w;
            accP[2][4] += a2 * t1.x; accP[2][5] += a2 * t1.y; accP[2][6] += a2 * t1.z; accP[2][7] += a2 * t1.w;
            accP[3][0] += a3 * t0.x; accP[3][1] += a3 * t0.y; accP[3][2] += a3 * t0.z; accP[3][3] += a3 * t0.w;
            accP[3][4] += a3 * t1.x; accP[3][5] += a3 * t1.y; accP[3][6] += a3 * t1.z; accP[3][7] += a3 * t1.w;
            accQ[0][0] += a0 * u0.x; accQ[0][1] += a0 * u0.y; accQ[0][2] += a0 * u0.z; accQ[0][3] += a0 * u0.w;
            accQ[0][4] += a0 * u1.x; accQ[0][5] += a0 * u1.y; accQ[0][6] += a0 * u1.z; accQ[0][7] += a0 * u1.w;
            accQ[1][0] += a1 * u0.x; accQ[1][1] += a1 * u0.y; accQ[1][2] += a1 * u0.z; accQ[1][3] += a1 * u0.w;
            accQ[1][4] += a1 * u1.x; accQ[1][5] += a1 * u1.y; accQ[1][6] += a1 * u1.z; accQ[1][7] += a1 * u1.w;
            accQ[2][0] += a2 * u0.x; accQ[2][1] += a2 * u0.y; accQ[2][2] += a2 * u0.z; accQ[2][3] += a2 * u0.w;
            accQ[2][4] += a2 * u1.x; accQ[2][5] += a2 * u1.y; accQ[2][6] += a2 * u1.z; accQ[2][7] += a2 * u1.w;
            accQ[3][0] += a3 * u0.x; accQ[3][1] += a3 * u0.y; accQ[3][2] += a3 * u0.z; accQ[3][3] += a3 * u0.w;
            accQ[3][4] += a3 * u1.x; accQ[3][5] += a3 * u1.y; accQ[3][6] += a3 * u1.z; accQ[3][7] += a3 * u1.w;
        }
        __syncthreads();
    }
#pragma unroll
    for (int i = 0; i < 4; ++i) {
        int gr = r0 + rc * 4 + i;
        if (gr < M) {
            *(float4*)(outP + (size_t)gr * 128 + jc * 8)     = make_float4(accP[i][0], accP[i][1], accP[i][2], accP[i][3]);
            *(float4*)(outP + (size_t)gr * 128 + jc * 8 + 4) = make_float4(accP[i][4], accP[i][5], accP[i][6], accP[i][7]);
            *(float4*)(outQ + (size_t)gr * 128 + jc * 8)     = make_float4(accQ[i][0], accQ[i][1], accQ[i][2], accQ[i][3]);
            *(float4*)(outQ + (size_t)gr * 128 + jc * 8 + 4) = make_float4(accQ[i][4], accQ[i][5], accQ[i][6], accQ[i][7]);
        }
    }
}

// ---------------- aggregate (gather): h_next[n] = b + hw[n]*dinv[n]^2 + sum_csr hw[src]*w ----
__global__ __launch_bounds__(256) void k_aggregate(const float* __restrict__ hw,
                                                   const float* __restrict__ b,
                                                   const float* __restrict__ dinv,
                                                   const int* __restrict__ rowStart,
                                                   const int2* __restrict__ csr,
                                                   float* __restrict__ hout) {
    int wid = (blockIdx.x * blockDim.x + threadIdx.x) >> 6;  // one wave per node
    int lane = threadIdx.x & 63;
    if (wid >= N_NODES) return;
    int n = wid;
    float di = dinv[n];
    float2 acc = *(const float2*)(b + lane * 2);
    float2 hv = *(const float2*)(hw + (size_t)n * 128 + lane * 2);
    acc.x += hv.x * di * di;
    acc.y += hv.y * di * di;
    int s0 = rowStart[n], s1 = rowStart[n + 1];
    for (int k = s0; k < s1; ++k) {
        int2 c = csr[k];
        float w = __int_as_float(c.y);
        float2 v = *(const float2*)(hw + (size_t)c.x * 128 + lane * 2);
        acc.x += v.x * w;
        acc.y += v.y * w;
    }
    *(float2*)(hout + (size_t)n * 128 + lane * 2) = acc;
}

// ---------------- edge final: out[e] = relu(P[s] + Q[d] + b1) @ W2 + b2 ----------------
__global__ __launch_bounds__(256) void k_edge_final(const float* __restrict__ P,
                                                    const float* __restrict__ Q,
                                                    const int* __restrict__ ei,
                                                    const float* __restrict__ b1,
                                                    const float* __restrict__ W2,
                                                    const float* __restrict__ b2,
                                                    float* __restrict__ out) {
    int t = blockIdx.x * 256 + threadIdx.x;
    int e = t >> 4;       // 16 lanes per edge
    int l = t & 15;       // lane owns cols l*8 .. l*8+7
    if (e >= N_EDGES) return;
    int s = ei[e], d = ei[N_EDGES + e];
    const float* prow = P + (size_t)s * 128 + l * 8;
    const float* qrow = Q + (size_t)d * 128 + l * 8;
    float4 pa = *(const float4*)(prow);
    float4 pb = *(const float4*)(prow + 4);
    float4 qa = *(const float4*)(qrow);
    float4 qb = *(const float4*)(qrow + 4);
    float4 ba = *(const float4*)(b1 + l * 8);
    float4 bb = *(const float4*)(b1 + l * 8 + 4);
    float z[8];
    z[0] = fmaxf(pa.x + qa.x + ba.x, 0.f);
    z[1] = fmaxf(pa.y + qa.y + ba.y, 0.f);
    z[2] = fmaxf(pa.z + qa.z + ba.z, 0.f);
    z[3] = fmaxf(pa.w + qa.w + ba.w, 0.f);
    z[4] = fmaxf(pb.x + qb.x + bb.x, 0.f);
    z[5] = fmaxf(pb.y + qb.y + bb.y, 0.f);
    z[6] = fmaxf(pb.z + qb.z + bb.z, 0.f);
    z[7] = fmaxf(pb.w + qb.w + bb.w, 0.f);
    float o0 = 0.f, o1 = 0.f, o2 = 0.f;
#pragma unroll
    for (int k = 0; k < 8; ++k) {
        const float* w2r = W2 + (size_t)(l * 8 + k) * 3;
        o0 += z[k] * w2r[0];
        o1 += z[k] * w2r[1];
        o2 += z[k] * w2r[2];
    }
#pragma unroll
    for (int m = 1; m < 16; m <<= 1) {
        o0 += __shfl_xor(o0, m);
        o1 += __shfl_xor(o1, m);
        o2 += __shfl_xor(o2, m);
    }
    if (l == 0) {
        float* op = out + (size_t)e * 3;
        op[0] = o0 + b2[0];
        op[1] = o1 + b2[1];
        op[2] = o2 + b2[2];
    }
}

extern "C" void kernel_launch(void* const* d_in, const int* in_sizes, int n_in,
                              void* d_out, int out_size, void* d_ws, size_t ws_size,
                              hipStream_t stream) {
    const float* x     = (const float*)d_in[0];
    const int*   ei    = (const int*)d_in[1];
    const float* W_enc = (const float*)d_in[2];
    const float* b_enc = (const float*)d_in[3];
    const float* Wg[3] = {(const float*)d_in[4], (const float*)d_in[6], (const float*)d_in[8]};
    const float* bg[3] = {(const float*)d_in[5], (const float*)d_in[7], (const float*)d_in[9]};
    const float* W_m1  = (const float*)d_in[10];
    const float* b_m1  = (const float*)d_in[11];
    const float* W_m2  = (const float*)d_in[12];
    const float* b_m2  = (const float*)d_in[13];
    float* out = (float*)d_out;

    // workspace: hA 25.6M | hB 25.6M | csr 6.4M | dinv | rowStart | cursor | blockSums
    char* w = (char*)d_ws;
    float* hA       = (float*)w;                         w += (size_t)N_NODES * HID * 4;
    float* hB       = (float*)w;                         w += (size_t)N_NODES * HID * 4;
    int2*  csr      = (int2*)w;                          w += (size_t)N_EDGES * 8;
    float* dinv     = (float*)w;                         w += (size_t)N_NODES * 4;
    int*   rowStart = (int*)w;                           w += (size_t)(N_NODES + 1) * 4;
    int*   cursor   = (int*)w;                           w += (size_t)N_NODES * 4;
    int*   blockSums= (int*)w;

    // --- CSR build (once; reused across 3 layers) ---
    k_zero_cnt<<<(N_NODES + 255) / 256, 256, 0, stream>>>(cursor);
    k_count<<<(N_EDGES + 255) / 256, 256, 0, stream>>>(ei, cursor);
    k_scan1<<<N_SCAN_BLOCKS, SCAN_BLK, 0, stream>>>(cursor, rowStart, blockSums, dinv);
    k_scan2<<<1, 64, 0, stream>>>(blockSums);
    k_scan3<<<N_SCAN_BLOCKS, SCAN_BLK, 0, stream>>>(rowStart, blockSums, cursor);
    k_fill<<<(N_EDGES + 255) / 256, 256, 0, stream>>>(ei, dinv, rowStart, cursor, csr);

    k_encoder<<<N_NODES * HID / 256, 256, 0, stream>>>(x, W_enc, b_enc, hA);

    for (int l = 0; l < 3; ++l) {
        k_gemm_node<<<(N_NODES + 63) / 64, 256, 0, stream>>>(hA, Wg[l], hB, N_NODES);
        k_aggregate<<<(N_NODES * 64 + 255) / 256, 256, 0, stream>>>(hB, bg[l], dinv, rowStart, csr, hA);
    }

    // P = relu(h)@W1_top -> hB ; Q = relu(h)@W1_bot -> hA (in-place safe)
    k_gemm_pq<<<(N_NODES + 63) / 64, 256, 0, stream>>>(hA, W_m1, W_m1 + 128 * 128, hB, hA, N_NODES);

    k_edge_final<<<N_EDGES * 16 / 256, 256, 0, stream>>>(hB, hA, ei, b_m1, W_m2, b_m2, out);
}